// Round 1
// baseline (139.109 us; speedup 1.0000x reference)
//
#include <hip/hip_runtime.h>

// Problem constants
#define Bc  32
#define Nc  16
#define Tc  64
#define Hc  256
#define NTc 1024   // N*T

// Workspace layout (float offsets):
//   M    [B*T*H]     = 524288   (mean over neighbors, includes /16)
//   P    [B*NT*T]    = 2097152  (per-row softmax over the 64 unique logits)
//   Wsum [B*T]       = 2048     (column sums of P, atomically accumulated)
#define M_OFF  0
#define P_OFF  (Bc * Tc * Hc)
#define W_OFF  (P_OFF + Bc * NTc * Tc)

// ---------------------------------------------------------------------------
// Kernel 1: M[b,t,h] = (1/16) * sum_i neigh[b,i,t,h]
// grid 512 x 256 threads; one float4 per thread; coalesced in h.
// ---------------------------------------------------------------------------
__global__ __launch_bounds__(256) void mean_kernel(const float* __restrict__ neigh,
                                                   float* __restrict__ M) {
    int idx = blockIdx.x * 256 + threadIdx.x;   // over B*T*(H/4) = 131072
    int h4 = idx & 63;                          // float4 index within H
    int bt = idx >> 6;                          // b*T + t
    int b  = bt >> 6;
    int t  = bt & 63;
    const float4* p = (const float4*)neigh
                    + ((size_t)b * Nc * Tc * Hc + (size_t)t * Hc) / 4 + h4;
    float4 s = make_float4(0.f, 0.f, 0.f, 0.f);
#pragma unroll
    for (int i = 0; i < Nc; i++) {
        float4 v = p[(size_t)i * (Tc * Hc / 4)];
        s.x += v.x; s.y += v.y; s.z += v.z; s.w += v.w;
    }
    const float r = 1.0f / 16.0f;
    s.x *= r; s.y *= r; s.z *= r; s.w *= r;
    ((float4*)M)[idx] = s;
}

// ---------------------------------------------------------------------------
// Kernel 2: per block: one (b, 64-row q chunk).
//   S[64q][64t] = X[64][256] @ node^T, scaled by 1/sqrt(nb), softmax over t,
//   write P, accumulate column sums into Wsum (atomic).
// 256 threads, 4x4 register tile per thread (tx -> t groups, ty -> q groups).
// ---------------------------------------------------------------------------
__global__ __launch_bounds__(256) void attn_p_kernel(const float* __restrict__ neigh,
                                                     const float* __restrict__ node,
                                                     const int*   __restrict__ nbr,
                                                     float* __restrict__ P,
                                                     float* __restrict__ Wsum) {
    __shared__ float Xs[64][68];   // [q][k-chunk]
    __shared__ float Ns[64][68];   // [k-chunk][t]  (transposed node)

    int b  = blockIdx.x >> 4;
    int q0 = (blockIdx.x & 15) << 6;
    int tx = threadIdx.x & 15;
    int ty = threadIdx.x >> 4;

    // neighbors_number: reference says int64; harness may upload int32.
    // Values are in [1,16] so nbr[1]==0 <=> buffer is int64 (high word of elem 0).
    int nb = (nbr[1] == 0) ? nbr[2 * b] : nbr[b];
    float rscale = rsqrtf((float)nb);

    const float* Xg = neigh + (size_t)b * (Nc * Tc * Hc) + (size_t)q0 * Hc;
    const float* Ng = node  + (size_t)b * (Tc * Hc);

    float acc[4][4];
#pragma unroll
    for (int i = 0; i < 4; i++)
#pragma unroll
        for (int j = 0; j < 4; j++) acc[i][j] = 0.f;

    for (int k0 = 0; k0 < Hc; k0 += 64) {
        // Stage X chunk (row-major) and node chunk (transposed to [k][t]).
#pragma unroll
        for (int r = 0; r < 4; r++) {
            int row = r * 16 + ty;
            float4 xv = *(const float4*)(Xg + (size_t)row * Hc + k0 + tx * 4);
            *(float4*)&Xs[row][tx * 4] = xv;
            float4 nv = *(const float4*)(Ng + (size_t)row * Hc + k0 + tx * 4);
            Ns[tx * 4 + 0][row] = nv.x;
            Ns[tx * 4 + 1][row] = nv.y;
            Ns[tx * 4 + 2][row] = nv.z;
            Ns[tx * 4 + 3][row] = nv.w;
        }
        __syncthreads();

#pragma unroll
        for (int kk = 0; kk < 64; kk += 4) {
            float xq[4][4];
#pragma unroll
            for (int i = 0; i < 4; i++)
                *(float4*)&xq[i][0] = *(const float4*)&Xs[ty * 4 + i][kk];
#pragma unroll
            for (int s = 0; s < 4; s++) {
                float4 nv = *(const float4*)&Ns[kk + s][tx * 4];
#pragma unroll
                for (int i = 0; i < 4; i++) {
                    acc[i][0] += xq[i][s] * nv.x;
                    acc[i][1] += xq[i][s] * nv.y;
                    acc[i][2] += xq[i][s] * nv.z;
                    acc[i][3] += xq[i][s] * nv.w;
                }
            }
        }
        __syncthreads();
    }

    // Scale, softmax over t (row q is spread over 16 tx-lanes x 4 regs).
    float colsum[4] = {0.f, 0.f, 0.f, 0.f};
#pragma unroll
    for (int i = 0; i < 4; i++) {
#pragma unroll
        for (int j = 0; j < 4; j++) acc[i][j] *= rscale;
        float m = fmaxf(fmaxf(acc[i][0], acc[i][1]), fmaxf(acc[i][2], acc[i][3]));
#pragma unroll
        for (int d = 1; d < 16; d <<= 1) m = fmaxf(m, __shfl_xor(m, d));
        float e0 = __expf(acc[i][0] - m);
        float e1 = __expf(acc[i][1] - m);
        float e2 = __expf(acc[i][2] - m);
        float e3 = __expf(acc[i][3] - m);
        float s = e0 + e1 + e2 + e3;
#pragma unroll
        for (int d = 1; d < 16; d <<= 1) s += __shfl_xor(s, d);
        float inv = 1.0f / s;
        float4 pv = make_float4(e0 * inv, e1 * inv, e2 * inv, e3 * inv);
        colsum[0] += pv.x; colsum[1] += pv.y; colsum[2] += pv.z; colsum[3] += pv.w;
        *(float4*)(P + ((size_t)b * NTc + q0 + ty * 4 + i) * Tc + tx * 4) = pv;
    }

    // Column-sum reduce over the 4 ty-values inside each wave (tid bits 4,5),
    // then one atomicAdd per (wave, t).
#pragma unroll
    for (int j = 0; j < 4; j++) {
        colsum[j] += __shfl_xor(colsum[j], 16);
        colsum[j] += __shfl_xor(colsum[j], 32);
    }
    if ((ty & 3) == 0) {
#pragma unroll
        for (int j = 0; j < 4; j++)
            atomicAdd(&Wsum[b * Tc + tx * 4 + j], colsum[j]);
    }
}

// ---------------------------------------------------------------------------
// Kernel 3: output[64q][64h] = P[64q][64t] @ M[64t][64h]  (per block tile)
// grid = B * 16(qc) * 4(hc) = 2048 blocks, 256 threads, 4x4 per thread.
// ---------------------------------------------------------------------------
__global__ __launch_bounds__(256) void out_kernel(const float* __restrict__ P,
                                                  const float* __restrict__ M,
                                                  float* __restrict__ out) {
    __shared__ float Ps[64][68];   // [q][t]
    __shared__ float Ms[64][68];   // [t][h-chunk]

    int bk = blockIdx.x;
    int b  = bk >> 6;
    int q0 = ((bk >> 2) & 15) << 6;
    int h0 = (bk & 3) << 6;
    int tx = threadIdx.x & 15;
    int ty = threadIdx.x >> 4;

#pragma unroll
    for (int r = 0; r < 4; r++) {
        int row = r * 16 + ty;
        *(float4*)&Ps[row][tx * 4] =
            *(const float4*)(P + ((size_t)b * NTc + q0 + row) * Tc + tx * 4);
        *(float4*)&Ms[row][tx * 4] =
            *(const float4*)(M + ((size_t)b * Tc + row) * Hc + h0 + tx * 4);
    }
    __syncthreads();

    float acc[4][4];
#pragma unroll
    for (int i = 0; i < 4; i++)
#pragma unroll
        for (int j = 0; j < 4; j++) acc[i][j] = 0.f;

#pragma unroll
    for (int t0 = 0; t0 < 64; t0 += 4) {
        float pq[4][4];
#pragma unroll
        for (int i = 0; i < 4; i++)
            *(float4*)&pq[i][0] = *(const float4*)&Ps[ty * 4 + i][t0];
#pragma unroll
        for (int s = 0; s < 4; s++) {
            float4 mv = *(const float4*)&Ms[t0 + s][tx * 4];
#pragma unroll
            for (int i = 0; i < 4; i++) {
                acc[i][0] += pq[i][s] * mv.x;
                acc[i][1] += pq[i][s] * mv.y;
                acc[i][2] += pq[i][s] * mv.z;
                acc[i][3] += pq[i][s] * mv.w;
            }
        }
    }

#pragma unroll
    for (int i = 0; i < 4; i++) {
        float4 v = make_float4(acc[i][0], acc[i][1], acc[i][2], acc[i][3]);
        *(float4*)(out + ((size_t)b * NTc + q0 + ty * 4 + i) * Hc + h0 + tx * 4) = v;
    }
}

// ---------------------------------------------------------------------------
// Kernel 4: W[b,i,t] = Wsum[b,t] / 16  (independent of i)
// ---------------------------------------------------------------------------
__global__ __launch_bounds__(256) void wexp_kernel(const float* __restrict__ Wsum,
                                                   float* __restrict__ Wout) {
    int idx = blockIdx.x * 256 + threadIdx.x;   // over B*N*T = 32768
    int b = idx >> 10;
    int t = idx & 63;
    Wout[idx] = Wsum[b * Tc + t] * (1.0f / 16.0f);
}

// ---------------------------------------------------------------------------
extern "C" void kernel_launch(void* const* d_in, const int* in_sizes, int n_in,
                              void* d_out, int out_size, void* d_ws, size_t ws_size,
                              hipStream_t stream) {
    const float* node  = (const float*)d_in[0];   // (B,T,H)
    const float* neigh = (const float*)d_in[1];   // (B,N,T,H)
    const int*   nbr   = (const int*)d_in[2];     // (B,) int32 or int64 (detected)

    float* out = (float*)d_out;                   // output (B,NT,H) then W (B,N,T)
    float* ws  = (float*)d_ws;
    float* Mw  = ws + M_OFF;
    float* Pw  = ws + P_OFF;
    float* Ww  = ws + W_OFF;

    hipMemsetAsync(Ww, 0, Bc * Tc * sizeof(float), stream);

    mean_kernel  <<<512, 256, 0, stream>>>(neigh, Mw);
    attn_p_kernel<<<512, 256, 0, stream>>>(neigh, node, nbr, Pw, Ww);
    out_kernel   <<<2048, 256, 0, stream>>>(Pw, Mw, out);
    wexp_kernel  <<<128, 256, 0, stream>>>(Ww, out + (size_t)Bc * NTc * Hc);
}